// Round 1
// baseline (366.543 us; speedup 1.0000x reference)
//
#include <hip/hip_runtime.h>

#define Nq 300
#define Tq 12
#define Dq 64
#define Mq 16
#define BTq 384
#define DDq (Dq*Dq)      // 4096
#define Fq (Dq*3)        // 192
#define NP 320           // padded k-extent of transposed bf16 buffers

typedef short bf8_t __attribute__((ext_vector_type(8)));
typedef float f4_t  __attribute__((ext_vector_type(4)));

__device__ __forceinline__ unsigned short f2bf(float f) {
    unsigned u = __float_as_uint(f);
    u = (u + 0x7FFFu + ((u >> 16) & 1u)) >> 16;
    return (unsigned short)u;
}
__device__ __forceinline__ float bf2f(unsigned short u) {
    return __uint_as_float((unsigned)u << 16);
}
__device__ __forceinline__ float4 ld4(const float* p) { return *(const float4*)p; }

__device__ __forceinline__ bf8_t pack8(float4 a, float4 b) {
    bf8_t r;
    r[0] = (short)f2bf(a.x); r[1] = (short)f2bf(a.y);
    r[2] = (short)f2bf(a.z); r[3] = (short)f2bf(a.w);
    r[4] = (short)f2bf(b.x); r[5] = (short)f2bf(b.y);
    r[6] = (short)f2bf(b.z); r[7] = (short)f2bf(b.w);
    return r;
}

__device__ __forceinline__ float gatef(float p) {
    float pc = fminf(fmaxf(p, -30.f), 30.f);
    float sig = 1.f / (1.f + __expf(-pc));
    float e2  = __expf(2.f * pc);
    float th  = (e2 - 1.f) / (e2 + 1.f);
    return sig * th;
}

// ---- Merged front-end: 1164 blocks.
//  [0,400)    ABt tiles (MFMA-C-tiled alpha/beta pairs)
//  [400,700)  Wt per-node weights (n = vb-400)
//  [700,780)  adjWb/adjBp padding
//  [780,1164) X transpose -> Xp_t, Xp_nb
__global__ void __launch_bounds__(256) kprep_all(
    const float* __restrict__ a1, const float* __restrict__ a2,
    const float* __restrict__ b1, const float* __restrict__ b2,
    const float* __restrict__ w1, const float* __restrict__ w2,
    const float* __restrict__ adjW, const float* __restrict__ adjB,
    const float* __restrict__ X,
    unsigned* __restrict__ ABt, unsigned short* __restrict__ Wt,
    unsigned short* __restrict__ adjWb, float* __restrict__ adjBp,
    unsigned short* __restrict__ Xp_t, unsigned short* __restrict__ Xp_nb)
{
    __shared__ char smem[64 * 308 * 2];    // 39424 B union
    const int vb = blockIdx.x;
    const int tid = threadIdx.x;

    if (vb < 400) {
        // ABt: tile = ((qi*5+c)*4+w)*5+nt ; n = qi*80+nt*16+(lane&15), k = c*64+w*16+(lane>>4)*4+reg
        const int tile = vb;
        const int reg = tid & 3, lane = tid >> 2;
        const int nt = tile % 5;  int r1 = tile / 5;
        const int w  = r1 % 4;    int r2 = r1 / 4;
        const int c  = r2 % 5;    const int qi = r2 / 5;
        const int n = qi*80 + nt*16 + (lane & 15);
        const int k = c*64 + w*16 + (lane >> 4)*4 + reg;
        unsigned outv = 0u;
        if (n < Nq && k < Nq) {
            float sa = 0.f, sb = 0.f;
            #pragma unroll
            for (int m = 0; m < Mq; ++m) {
                sa = fmaf(a1[n*Mq+m], a2[m*Nq+k], sa);
                sb = fmaf(b1[n*Mq+m], b2[m*Nq+k], sb);
            }
            outv = ((unsigned)f2bf(sb) << 16) | (unsigned)f2bf(sa);
        }
        ABt[tile*256 + tid] = outv;
    } else if (vb < 700) {
        // Wt bf16 [n][d][k] = (trainW1@trainW2)[n, k*64+d]
        float* sT = (float*)smem;          // [64][65]
        __shared__ float sw1[Mq];
        const int n = vb - 400;
        if (tid < Mq) sw1[tid] = w1[n*Mq + tid];
        __syncthreads();
        for (int i = tid; i < DDq; i += 256) {
            int k = i >> 6, d = i & 63;
            float s = 0.f;
            #pragma unroll
            for (int m = 0; m < Mq; ++m) s = fmaf(sw1[m], w2[m*DDq + i], s);
            sT[d*65 + k] = s;
        }
        __syncthreads();
        for (int i = tid; i < DDq; i += 256) {
            int d = i >> 6, k = i & 63;
            Wt[(size_t)n*DDq + i] = f2bf(sT[d*65 + k]);
        }
    } else if (vb < 780) {
        int e = (vb - 700) * 256 + tid;
        if (e < NP * 64) {
            int k = e >> 6, d = e & 63;
            adjWb[e] = (k < Nq) ? f2bf(adjW[k*Dq + d]) : (unsigned short)0;
        }
        if (e < NP) adjBp[e] = (e < Nq) ? adjB[e] : 0.f;
    } else {
        // X [b][d][n][t] -> Xp_t bf16 [bt][64][320] and Xp_nb bf16 [n][384][64]
        unsigned short* sT = (unsigned short*)smem;   // [64][308]
        const int bx = vb - 780;
        const int b = bx / 12, tile = bx % 12;
        const int n0 = tile * 25;
        for (int i = tid; i < 64 * 300; i += 256) {
            int d = i / 300, j = i - d * 300;
            sT[d*308 + j] = f2bf(X[(size_t)(b*64 + d)*3600 + n0*12 + j]);
        }
        __syncthreads();
        for (int wi = tid; wi < 12 * 64 * 25; wi += 256) {
            int nl = wi % 25, rem = wi / 25;
            int d = rem % 64, t = rem / 64;
            Xp_t[((size_t)(b*Tq + t)*64 + d)*NP + n0 + nl] = sT[d*308 + nl*12 + t];
        }
        if (tile == 11) {
            for (int wi = tid; wi < 12 * 64 * 20; wi += 256) {
                int e = wi % 20, rem = wi / 20;
                int d = rem % 64, t = rem / 64;
                Xp_t[((size_t)(b*Tq + t)*64 + d)*NP + 300 + e] = 0;
            }
        }
        for (int wi = tid; wi < 25 * 12 * 64; wi += 256) {
            int d = wi & 63, rem = wi >> 6;
            int t = rem % 12, nl = rem / 12;
            Xp_nb[((size_t)(n0 + nl)*BTq + b*Tq + t)*64 + d] = sT[d*308 + nl*12 + t];
        }
    }
}

// bf16 transpose: H_nb [n][384][64] -> H_t [bt][64][320] (cols>=300 zero)
__global__ void __launch_bounds__(256) ktr2(const unsigned short* __restrict__ Hnb,
                                            unsigned short* __restrict__ Ht) {
    __shared__ unsigned short sT[64 * 308];
    const int bt = blockIdx.x;
    const int tid = threadIdx.x;
    for (int i = tid; i < 300 * 64; i += 256) {
        int n = i >> 6, d = i & 63;
        sT[d*308 + n] = Hnb[((size_t)n*BTq + bt)*64 + d];
    }
    __syncthreads();
    for (int wi = tid; wi < 64 * 80; wi += 256) {
        int kq = wi % 80, d = wi / 80;
        ushort4 o;
        int k = kq * 4;
        o.x = (k+0 < Nq) ? sT[d*308 + k+0] : (unsigned short)0;
        o.y = (k+1 < Nq) ? sT[d*308 + k+1] : (unsigned short)0;
        o.z = (k+2 < Nq) ? sT[d*308 + k+2] : (unsigned short)0;
        o.w = (k+3 < Nq) ? sT[d*308 + k+3] : (unsigned short)0;
        *(ushort4*)&Ht[((size_t)bt*64 + d)*NP + k] = o;
    }
}

// ---- NEW: materialize A once (hop-invariant). A_t bf16 [bt][300][320].
// Grid 1536 = (bt, n-quarter of 80). No LDS, no barriers.
__global__ void __launch_bounds__(256) kA(
    const float* __restrict__ te,              // [B,N,T,D] fp32
    const unsigned short* __restrict__ adjWb,  // [320][64]
    const float* __restrict__ adjBp,           // [320]
    const unsigned* __restrict__ ABt,          // tiled alpha/beta pairs
    unsigned short* __restrict__ At)           // [bt][300][320] bf16
{
    const int bt = blockIdx.x >> 2, qi = blockIdx.x & 3;
    const int b = bt / Tq, t = bt - b * Tq;
    const int nbase = qi * 80;
    const int tid = threadIdx.x;
    const int w = tid >> 6, lane = tid & 63, quad = lane >> 4, l16 = lane & 15;

    bf8_t tb0[5], tb1[5];
    #pragma unroll
    for (int nt = 0; nt < 5; ++nt) {
        int n = nbase + nt*16 + l16; if (n > Nq-1) n = Nq-1;
        const float* ter = te + (((size_t)b*Nq + n)*Tq + t)*Dq;
        tb0[nt] = pack8(ld4(ter + quad*8),      ld4(ter + quad*8 + 4));
        tb1[nt] = pack8(ld4(ter + 32 + quad*8), ld4(ter + 36 + quad*8));
    }
    #pragma unroll
    for (int c = 0; c < 5; ++c) {
        const int cbase = c * 64;
        const unsigned short* ar = adjWb + (cbase + w*16 + l16)*64;
        bf8_t ka0 = *(const bf8_t*)(ar + quad*8);
        bf8_t ka1 = *(const bf8_t*)(ar + 32 + quad*8);
        float4 bias4 = ld4(adjBp + cbase + w*16 + quad*4);
        const unsigned* abbase = ABt + ((((size_t)qi*5 + c)*4 + w)*5)*256 + lane*4;
        #pragma unroll
        for (int nt = 0; nt < 5; ++nt) {
            f4_t p = {0.f, 0.f, 0.f, 0.f};
            p = __builtin_amdgcn_mfma_f32_16x16x32_bf16(ka0, tb0[nt], p, 0, 0, 0);
            p = __builtin_amdgcn_mfma_f32_16x16x32_bf16(ka1, tb1[nt], p, 0, 0, 0);
            uint4 ab = *(const uint4*)(abbase + nt*256);
            ushort4 o4;
            {
                float sv = __sinf(p[0] + bias4.x);
                o4.x = f2bf(fmaxf(fmaf(__uint_as_float(ab.x << 16), sv,
                                       __uint_as_float(ab.x & 0xFFFF0000u)), 0.f));
            }
            {
                float sv = __sinf(p[1] + bias4.y);
                o4.y = f2bf(fmaxf(fmaf(__uint_as_float(ab.y << 16), sv,
                                       __uint_as_float(ab.y & 0xFFFF0000u)), 0.f));
            }
            {
                float sv = __sinf(p[2] + bias4.z);
                o4.z = f2bf(fmaxf(fmaf(__uint_as_float(ab.z << 16), sv,
                                       __uint_as_float(ab.z & 0xFFFF0000u)), 0.f));
            }
            {
                float sv = __sinf(p[3] + bias4.w);
                o4.w = f2bf(fmaxf(fmaf(__uint_as_float(ab.w << 16), sv,
                                       __uint_as_float(ab.w & 0xFFFF0000u)), 0.f));
            }
            int n = nbase + nt*16 + l16;
            if (n < Nq)
                *(ushort4*)&At[((size_t)bt*Nq + n)*NP + cbase + w*16 + quad*4] = o4;
        }
    }
}

// ---- NEW: pure aggregation GEMM per bt: Hout[n,d] = sum_k A[n,k] * Hb[k,d].
// Grid 1536, XCD-swizzled so the 4 qi-blocks of one bt share an XCD L2.
// No LDS, no barriers; ~64 VGPR -> 8 blocks/CU.
__global__ void __launch_bounds__(256) kagg(
    const unsigned short* __restrict__ At,     // [bt][300][320]
    const unsigned short* __restrict__ Hb_t,   // [bt][64][320]
    unsigned short* __restrict__ Hout_nb)      // [300][384][64]
{
    const int g = blockIdx.x;
    const int xcd = g & 7, li = g >> 3;        // 192 blocks per xcd slot
    const int bt = xcd * 48 + (li % 48), qi = li / 48;
    const int tid = threadIdx.x;
    const int w = tid >> 6, lane = tid & 63, quad = lane >> 4, l16 = lane & 15;
    const int dcol = w*16 + l16;
    const int nbase = qi * 80;

    const unsigned short* hrow = Hb_t + ((size_t)bt*64 + dcol)*NP;
    const unsigned short* ab0  = At + (size_t)bt*Nq*NP;
    size_t aoff[5];
    #pragma unroll
    for (int rt = 0; rt < 5; ++rt) {
        int r = nbase + rt*16 + l16; if (r > Nq-1) r = Nq-1;
        aoff[rt] = (size_t)r * NP;
    }
    f4_t accO[5];
    #pragma unroll
    for (int rt = 0; rt < 5; ++rt) accO[rt] = (f4_t){0.f, 0.f, 0.f, 0.f};

    #pragma unroll
    for (int c = 0; c < 5; ++c) {
        const int cbase = c * 64;
        bf8_t v0 = *(const bf8_t*)(hrow + cbase + quad*8);
        bf8_t v1 = *(const bf8_t*)(hrow + cbase + 32 + quad*8);
        #pragma unroll
        for (int rt = 0; rt < 5; ++rt) {
            const unsigned short* arr = ab0 + aoff[rt] + cbase;
            bf8_t p0 = *(const bf8_t*)(arr + quad*8);
            bf8_t p1 = *(const bf8_t*)(arr + 32 + quad*8);
            accO[rt] = __builtin_amdgcn_mfma_f32_16x16x32_bf16(p0, v0, accO[rt], 0, 0, 0);
            accO[rt] = __builtin_amdgcn_mfma_f32_16x16x32_bf16(p1, v1, accO[rt], 0, 0, 0);
        }
    }
    #pragma unroll
    for (int rt = 0; rt < 5; ++rt) {
        #pragma unroll
        for (int reg = 0; reg < 4; ++reg) {
            int ng = nbase + rt*16 + quad*4 + reg;
            if (ng < Nq)
                Hout_nb[((size_t)ng*BTq + bt)*64 + dcol] = f2bf(accO[rt][reg]);
        }
    }
}

// Fused A-recompute + aggregation (FALLBACK path when workspace too small).
__global__ void __launch_bounds__(256) kfuse(
    const float* __restrict__ te,              // [B,N,T,D] fp32 (original input)
    const unsigned short* __restrict__ adjWb,  // [320][64]
    const float* __restrict__ adjBp,           // [320]
    const unsigned* __restrict__ ABt,          // tiled pairs
    const unsigned short* __restrict__ Hb_t,   // [bt][64][320]
    unsigned short* __restrict__ Hout_nb)      // [300][384][64]
{
    __shared__ unsigned short sPl[2][80 * 72];
    const int bt = blockIdx.x >> 2, qi = blockIdx.x & 3;
    const int b = bt / Tq, t = bt - b * Tq;
    const int nbase = qi * 80;
    const int tid = threadIdx.x;
    const int w = tid >> 6, lane = tid & 63, quad = lane >> 4, l16 = lane & 15;
    const int dcol = w*16 + l16;

    bf8_t tb0[5], tb1[5];
    #pragma unroll
    for (int nt = 0; nt < 5; ++nt) {
        int n = nbase + nt*16 + l16; if (n > Nq-1) n = Nq-1;
        const float* ter = te + (((size_t)b*Nq + n)*Tq + t)*Dq;
        tb0[nt] = pack8(ld4(ter + quad*8),      ld4(ter + quad*8 + 4));
        tb1[nt] = pack8(ld4(ter + 32 + quad*8), ld4(ter + 36 + quad*8));
    }
    f4_t accO[5];
    #pragma unroll
    for (int rt = 0; rt < 5; ++rt) accO[rt] = (f4_t){0.f, 0.f, 0.f, 0.f};

    for (int c = 0; c < 5; ++c) {
        const int cbase = c * 64;
        const unsigned short* ar = adjWb + (cbase + w*16 + l16)*64;
        bf8_t ka0 = *(const bf8_t*)(ar + quad*8);
        bf8_t ka1 = *(const bf8_t*)(ar + 32 + quad*8);
        float4 bias4 = ld4(adjBp + cbase + w*16 + quad*4);
        const unsigned* abbase = ABt + ((((size_t)qi*5 + c)*4 + w)*5)*256 + lane*4;
        unsigned short* sp = sPl[c & 1];
        #pragma unroll
        for (int nt = 0; nt < 5; ++nt) {
            f4_t p = {0.f, 0.f, 0.f, 0.f};
            p = __builtin_amdgcn_mfma_f32_16x16x32_bf16(ka0, tb0[nt], p, 0, 0, 0);
            p = __builtin_amdgcn_mfma_f32_16x16x32_bf16(ka1, tb1[nt], p, 0, 0, 0);
            uint4 ab = *(const uint4*)(abbase + nt*256);
            ushort4 o4;
            {
                float sv = __sinf(p[0] + bias4.x);
                o4.x = f2bf(fmaxf(fmaf(__uint_as_float(ab.x << 16), sv,
                                       __uint_as_float(ab.x & 0xFFFF0000u)), 0.f));
            }
            {
                float sv = __sinf(p[1] + bias4.y);
                o4.y = f2bf(fmaxf(fmaf(__uint_as_float(ab.y << 16), sv,
                                       __uint_as_float(ab.y & 0xFFFF0000u)), 0.f));
            }
            {
                float sv = __sinf(p[2] + bias4.z);
                o4.z = f2bf(fmaxf(fmaf(__uint_as_float(ab.z << 16), sv,
                                       __uint_as_float(ab.z & 0xFFFF0000u)), 0.f));
            }
            {
                float sv = __sinf(p[3] + bias4.w);
                o4.w = f2bf(fmaxf(fmaf(__uint_as_float(ab.w << 16), sv,
                                       __uint_as_float(ab.w & 0xFFFF0000u)), 0.f));
            }
            *(ushort4*)&sp[(nt*16 + l16)*72 + w*16 + quad*4] = o4;
        }
        __syncthreads();
        const unsigned short* hr = Hb_t + ((size_t)bt*64 + dcol)*NP + cbase;
        bf8_t v0 = *(const bf8_t*)(hr + quad*8);
        bf8_t v1 = *(const bf8_t*)(hr + 32 + quad*8);
        #pragma unroll
        for (int rt = 0; rt < 5; ++rt) {
            bf8_t p0 = *(const bf8_t*)&sp[(rt*16 + l16)*72 + quad*8];
            bf8_t p1 = *(const bf8_t*)&sp[(rt*16 + l16)*72 + 32 + quad*8];
            accO[rt] = __builtin_amdgcn_mfma_f32_16x16x32_bf16(p0, v0, accO[rt], 0, 0, 0);
            accO[rt] = __builtin_amdgcn_mfma_f32_16x16x32_bf16(p1, v1, accO[rt], 0, 0, 0);
        }
    }
    #pragma unroll
    for (int rt = 0; rt < 5; ++rt) {
        #pragma unroll
        for (int reg = 0; reg < 4; ++reg) {
            int ng = nbase + rt*16 + quad*4 + reg;
            if (ng < Nq)
                Hout_nb[((size_t)ng*BTq + bt)*64 + dcol] = f2bf(accO[rt][reg]);
        }
    }
}

// Per-node matmul + gate. grid 1200 = (n, bt-quarter of 96). In-place safe per block.
__global__ void __launch_bounds__(256) kmm(
    const unsigned short* __restrict__ Hagg_nb,  // [n][384][64]
    const unsigned short* __restrict__ Xp_nb,    // [n][384][64]
    const unsigned short* __restrict__ Wt,       // [n][64][64]
    unsigned short* __restrict__ Hout_nb)        // [n][384][64]
{
    const int n = blockIdx.x >> 2, qi = blockIdx.x & 3;
    const int bt0 = qi * 96;
    const int tid = threadIdx.x;
    const int w = tid >> 6, lane = tid & 63, quad = lane >> 4, l16 = lane & 15;
    const int dcol = w*16 + l16;
    const unsigned short* wn = Wt + (size_t)n * DDq + dcol*64;
    bf8_t v0 = *(const bf8_t*)(wn + quad*8);
    bf8_t v1 = *(const bf8_t*)(wn + 32 + quad*8);
    f4_t acc[6];
    #pragma unroll
    for (int rt = 0; rt < 6; ++rt) acc[rt] = (f4_t){0.f, 0.f, 0.f, 0.f};
    #pragma unroll
    for (int rt = 0; rt < 6; ++rt) {
        int r = bt0 + rt*16 + l16;
        const unsigned short* row = Hagg_nb + ((size_t)n*BTq + r)*64;
        bf8_t a0 = *(const bf8_t*)(row + quad*8);
        bf8_t a1 = *(const bf8_t*)(row + 32 + quad*8);
        acc[rt] = __builtin_amdgcn_mfma_f32_16x16x32_bf16(a0, v0, acc[rt], 0, 0, 0);
        acc[rt] = __builtin_amdgcn_mfma_f32_16x16x32_bf16(a1, v1, acc[rt], 0, 0, 0);
    }
    __syncthreads();
    #pragma unroll
    for (int rt = 0; rt < 6; ++rt) {
        #pragma unroll
        for (int reg = 0; reg < 4; ++reg) {
            int r = bt0 + rt*16 + quad*4 + reg;
            size_t idx = ((size_t)n*BTq + r)*64 + dcol;
            float xp = bf2f(Xp_nb[idx]);
            Hout_nb[idx] = f2bf(gatef(xp + acc[rt][reg]));
        }
    }
}

// GCN epilogue: out[b,d,n,t] = gcnB[d] + [Xp|H1|H2]@gcnW[d,:]. grid 608 = (b, n-tile 16).
__global__ void __launch_bounds__(256) kgcn(
    const unsigned short* __restrict__ Xp_nb, const unsigned short* __restrict__ H1_nb,
    const unsigned short* __restrict__ H2_nb, const float* __restrict__ gcnW,
    const float* __restrict__ gcnB, float* __restrict__ out)
{
    const int b = blockIdx.x / 19, tile = blockIdx.x % 19;
    const int n0 = tile * 16;
    const int rows = (tile == 18) ? 144 : 192;
    const int tid = threadIdx.x;
    const int w = tid >> 6, lane = tid & 63, quad = lane >> 4, l16 = lane & 15;
    const int dcol = w*16 + l16;
    const float bias = gcnB[dcol];
    f4_t acc[12];
    #pragma unroll
    for (int rt = 0; rt < 12; ++rt) acc[rt] = (f4_t){0.f, 0.f, 0.f, 0.f};
    const unsigned short* bufs[3] = {Xp_nb, H1_nb, H2_nb};
    #pragma unroll
    for (int c = 0; c < 3; ++c) {
        const unsigned short* buf = bufs[c];
        const float* gwr = gcnW + (size_t)dcol*Fq + c*Dq;
        bf8_t v0 = pack8(ld4(gwr + quad*8),      ld4(gwr + quad*8 + 4));
        bf8_t v1 = pack8(ld4(gwr + 32 + quad*8), ld4(gwr + 36 + quad*8));
        #pragma unroll
        for (int rt = 0; rt < 12; ++rt) {
            int r = rt*16 + l16;
            int nl = r / 12, t = r - nl*12;
            int n = n0 + nl; if (n > Nq-1) n = Nq-1;
            const unsigned short* row = buf + ((size_t)n*BTq + b*Tq + t)*64;
            bf8_t a0 = *(const bf8_t*)(row + quad*8);
            bf8_t a1 = *(const bf8_t*)(row + 32 + quad*8);
            acc[rt] = __builtin_amdgcn_mfma_f32_16x16x32_bf16(a0, v0, acc[rt], 0, 0, 0);
            acc[rt] = __builtin_amdgcn_mfma_f32_16x16x32_bf16(a1, v1, acc[rt], 0, 0, 0);
        }
    }
    float* outd = out + (size_t)(b*Dq + dcol)*3600 + n0*12;
    #pragma unroll
    for (int rt = 0; rt < 12; ++rt) {
        if (rt*16 < rows) {
            int r0 = rt*16 + quad*4;
            float4 o = make_float4(acc[rt][0] + bias, acc[rt][1] + bias,
                                   acc[rt][2] + bias, acc[rt][3] + bias);
            *(float4*)&outd[r0] = o;
        }
    }
}

extern "C" void kernel_launch(void* const* d_in, const int* in_sizes, int n_in,
                              void* d_out, int out_size, void* d_ws, size_t ws_size,
                              hipStream_t stream) {
    (void)in_sizes; (void)n_in; (void)out_size;
    const float* X    = (const float*)d_in[0];
    const float* te   = (const float*)d_in[1];
    const float* adjW = (const float*)d_in[2];
    const float* adjB = (const float*)d_in[3];
    const float* w1   = (const float*)d_in[4];
    const float* w2   = (const float*)d_in[5];
    const float* a1   = (const float*)d_in[6];
    const float* a2   = (const float*)d_in[7];
    const float* b1   = (const float*)d_in[8];
    const float* b2   = (const float*)d_in[9];
    const float* gW   = (const float*)d_in[10];
    const float* gB   = (const float*)d_in[11];
    float* out = (float*)d_out;

    char* ws = (char*)d_ws;
    unsigned*       ABt    = (unsigned*)      (ws);               //    409,600
    unsigned short* adjWb  = (unsigned short*)(ws + 409600);      //  +  40,960 =    450,560
    float*          adjBp  = (float*)         (ws + 450560);      //  +   1,280 =    451,840
    unsigned short* Wt     = (unsigned short*)(ws + 451840);      //  +2,457,600 =  2,909,440
    unsigned short* Xp_t   = (unsigned short*)(ws + 2909440);     // +15,728,640 = 18,638,080
    unsigned short* Xp_nb  = (unsigned short*)(ws + 18638080);    // +14,745,600 = 33,383,680
    unsigned short* Hagg   = (unsigned short*)(ws + 33383680);    // +14,745,600 = 48,129,280
    unsigned short* H1_nb  = (unsigned short*)(ws + 48129280);    // +14,745,600 = 62,874,880
    // NEW path: A_t at 62,874,880 (+73,728,000 = 136,602,880); H1_t aliases Xp_t
    // (dead after hop-1 aggregation; ktr2 overwrite is stream-ordered-safe).
    unsigned short* At     = (unsigned short*)(ws + 62874880);
    const size_t NEED_NEW = 136602880;

    hipLaunchKernelGGL(kprep_all, dim3(1164), dim3(256), 0, stream,
                       a1, a2, b1, b2, w1, w2, adjW, adjB, X,
                       ABt, Wt, adjWb, adjBp, Xp_t, Xp_nb);

    if (ws_size >= NEED_NEW) {
        // materialize hop-invariant A once
        hipLaunchKernelGGL(kA, dim3(1536), dim3(256), 0, stream, te, adjWb, adjBp, ABt, At);
        // hop 1
        hipLaunchKernelGGL(kagg, dim3(1536), dim3(256), 0, stream, At, Xp_t, Hagg);
        hipLaunchKernelGGL(kmm,  dim3(1200), dim3(256), 0, stream, Hagg, Xp_nb, Wt, H1_nb);
        hipLaunchKernelGGL(ktr2, dim3(384),  dim3(256), 0, stream, H1_nb, Xp_t); // H1_t aliases Xp_t
        // hop 2
        hipLaunchKernelGGL(kagg, dim3(1536), dim3(256), 0, stream, At, Xp_t, Hagg);
        hipLaunchKernelGGL(kmm,  dim3(1200), dim3(256), 0, stream, Hagg, Xp_nb, Wt, Hagg); // in-place -> H2
    } else {
        // FALLBACK: original fused-recompute path (workspace too small for A_t)
        unsigned short* H1_t = (unsigned short*)(ws + 62874880 + 14745600); // 77,620,480.. wait: keep original offset
        H1_t = (unsigned short*)(ws + 62874880);
        // original layout had H1_t at 62,874,880 and H1_nb at 48,129,280 — but H1_nb
        // and H1_t must coexist; reuse original arrangement exactly:
        hipLaunchKernelGGL(kfuse, dim3(1536), dim3(256), 0, stream, te, adjWb, adjBp, ABt, Xp_t, Hagg);
        hipLaunchKernelGGL(kmm,   dim3(1200), dim3(256), 0, stream, Hagg, Xp_nb, Wt, H1_nb);
        hipLaunchKernelGGL(ktr2,  dim3(384),  dim3(256), 0, stream, H1_nb, Xp_t); // alias Xp_t (dead after hop1 kfuse)
        hipLaunchKernelGGL(kfuse, dim3(1536), dim3(256), 0, stream, te, adjWb, adjBp, ABt, Xp_t, Hagg);
        hipLaunchKernelGGL(kmm,   dim3(1200), dim3(256), 0, stream, Hagg, Xp_nb, Wt, Hagg);
    }
    // gcn epilogue
    hipLaunchKernelGGL(kgcn,  dim3(608), dim3(256), 0, stream, Xp_nb, H1_nb, Hagg, gW, gB, out);
}

// Round 2
// 295.900 us; speedup vs baseline: 1.2387x; 1.2387x over previous
//
#include <hip/hip_runtime.h>

#define Nq 300
#define Tq 12
#define Dq 64
#define Mq 16
#define BTq 384
#define DDq (Dq*Dq)      // 4096
#define Fq (Dq*3)        // 192
#define NP 320           // padded k-extent of transposed bf16 buffers

typedef short bf8_t __attribute__((ext_vector_type(8)));
typedef float f4_t  __attribute__((ext_vector_type(4)));

__device__ __forceinline__ unsigned short f2bf(float f) {
    unsigned u = __float_as_uint(f);
    u = (u + 0x7FFFu + ((u >> 16) & 1u)) >> 16;
    return (unsigned short)u;
}
__device__ __forceinline__ float bf2f(unsigned short u) {
    return __uint_as_float((unsigned)u << 16);
}
__device__ __forceinline__ float4 ld4(const float* p) { return *(const float4*)p; }

__device__ __forceinline__ bf8_t pack8(float4 a, float4 b) {
    bf8_t r;
    r[0] = (short)f2bf(a.x); r[1] = (short)f2bf(a.y);
    r[2] = (short)f2bf(a.z); r[3] = (short)f2bf(a.w);
    r[4] = (short)f2bf(b.x); r[5] = (short)f2bf(b.y);
    r[6] = (short)f2bf(b.z); r[7] = (short)f2bf(b.w);
    return r;
}

__device__ __forceinline__ float gatef(float p) {
    float pc = fminf(fmaxf(p, -30.f), 30.f);
    float sig = 1.f / (1.f + __expf(-pc));
    float e2  = __expf(2.f * pc);
    float th  = (e2 - 1.f) / (e2 + 1.f);
    return sig * th;
}

// ---- Merged front-end: 1548 blocks.
//  [0,400)    ABt tiles (MFMA-C-tiled alpha/beta pairs)
//  [400,700)  Wt per-node weights (n = vb-400)
//  [700,780)  adjWb/adjBp padding
//  [780,1548) X transpose -> Xp_t, Xp_nb (d-split halves, float4 loads)
__global__ void __launch_bounds__(256) kprep_all(
    const float* __restrict__ a1, const float* __restrict__ a2,
    const float* __restrict__ b1, const float* __restrict__ b2,
    const float* __restrict__ w1, const float* __restrict__ w2,
    const float* __restrict__ adjW, const float* __restrict__ adjB,
    const float* __restrict__ X,
    unsigned* __restrict__ ABt, unsigned short* __restrict__ Wt,
    unsigned short* __restrict__ adjWb, float* __restrict__ adjBp,
    unsigned short* __restrict__ Xp_t, unsigned short* __restrict__ Xp_nb)
{
    __shared__ char smem[64 * 308 * 2];    // 39424 B union (only [32][308]*2B used by X path)
    const int vb = blockIdx.x;
    const int tid = threadIdx.x;

    if (vb < 400) {
        const int tile = vb;
        const int reg = tid & 3, lane = tid >> 2;
        const int nt = tile % 5;  int r1 = tile / 5;
        const int w  = r1 % 4;    int r2 = r1 / 4;
        const int c  = r2 % 5;    const int qi = r2 / 5;
        const int n = qi*80 + nt*16 + (lane & 15);
        const int k = c*64 + w*16 + (lane >> 4)*4 + reg;
        unsigned outv = 0u;
        if (n < Nq && k < Nq) {
            float sa = 0.f, sb = 0.f;
            #pragma unroll
            for (int m = 0; m < Mq; ++m) {
                sa = fmaf(a1[n*Mq+m], a2[m*Nq+k], sa);
                sb = fmaf(b1[n*Mq+m], b2[m*Nq+k], sb);
            }
            outv = ((unsigned)f2bf(sb) << 16) | (unsigned)f2bf(sa);
        }
        ABt[tile*256 + tid] = outv;
    } else if (vb < 700) {
        float* sT = (float*)smem;          // [64][65]
        __shared__ float sw1[Mq];
        const int n = vb - 400;
        if (tid < Mq) sw1[tid] = w1[n*Mq + tid];
        __syncthreads();
        for (int i = tid; i < DDq; i += 256) {
            int k = i >> 6, d = i & 63;
            float s = 0.f;
            #pragma unroll
            for (int m = 0; m < Mq; ++m) s = fmaf(sw1[m], w2[m*DDq + i], s);
            sT[d*65 + k] = s;
        }
        __syncthreads();
        for (int i = tid; i < DDq; i += 256) {
            int d = i >> 6, k = i & 63;
            Wt[(size_t)n*DDq + i] = f2bf(sT[d*65 + k]);
        }
    } else if (vb < 780) {
        int e = (vb - 700) * 256 + tid;
        if (e < NP * 64) {
            int k = e >> 6, d = e & 63;
            adjWb[e] = (k < Nq) ? f2bf(adjW[k*Dq + d]) : (unsigned short)0;
        }
        if (e < NP) adjBp[e] = (e < Nq) ? adjB[e] : 0.f;
    } else {
        // X [b][d][n][t] -> Xp_t bf16 [bt][64][320] and Xp_nb bf16 [n][384][64]
        // 768 blocks: (b, tile of 12, d-half of 2)
        unsigned short* sT = (unsigned short*)smem;   // [32][308]
        const int bx = vb - 780;
        const int b = bx / 24, sub = bx % 24;
        const int tile = sub >> 1, half = sub & 1;
        const int n0 = tile * 25, d0 = half * 32;
        for (int i = tid; i < 32 * 75; i += 256) {
            int dl = i / 75, jq = i - dl*75, j = jq*4;
            float4 v = ld4(&X[(size_t)(b*64 + d0 + dl)*3600 + n0*12 + j]);
            ushort4 o;
            o.x = f2bf(v.x); o.y = f2bf(v.y); o.z = f2bf(v.z); o.w = f2bf(v.w);
            *(ushort4*)&sT[dl*308 + j] = o;
        }
        __syncthreads();
        for (int wi = tid; wi < 12 * 32 * 25; wi += 256) {
            int nl = wi % 25, rem = wi / 25;
            int dl = rem & 31, t = rem >> 5;
            Xp_t[((size_t)(b*Tq + t)*64 + d0 + dl)*NP + n0 + nl] = sT[dl*308 + nl*12 + t];
        }
        if (tile == 11) {
            for (int wi = tid; wi < 12 * 32 * 20; wi += 256) {
                int e = wi % 20, rem = wi / 20;
                int dl = rem & 31, t = rem >> 5;
                Xp_t[((size_t)(b*Tq + t)*64 + d0 + dl)*NP + 300 + e] = 0;
            }
        }
        for (int wi = tid; wi < 25 * 12 * 8; wi += 256) {
            int dg = wi & 7, rem = wi >> 3;
            int t = rem % 12, nl = rem / 12;
            ushort4 o;
            o.x = sT[(dg*4+0)*308 + nl*12 + t];
            o.y = sT[(dg*4+1)*308 + nl*12 + t];
            o.z = sT[(dg*4+2)*308 + nl*12 + t];
            o.w = sT[(dg*4+3)*308 + nl*12 + t];
            *(ushort4*)&Xp_nb[((size_t)(n0+nl)*BTq + b*Tq + t)*64 + d0 + dg*4] = o;
        }
    }
}

// bf16 transpose: H_nb [n][384][64] -> H_t [bt][64][320] (cols>=300 zero)
__global__ void __launch_bounds__(256) ktr2(const unsigned short* __restrict__ Hnb,
                                            unsigned short* __restrict__ Ht) {
    __shared__ unsigned short sT[64 * 308];
    const int bt = blockIdx.x;
    const int tid = threadIdx.x;
    for (int i = tid; i < 300 * 16; i += 256) {
        int nl = i >> 4, dg = i & 15;
        ushort4 v = *(const ushort4*)&Hnb[((size_t)nl*BTq + bt)*64 + dg*4];
        sT[(dg*4+0)*308 + nl] = v.x;
        sT[(dg*4+1)*308 + nl] = v.y;
        sT[(dg*4+2)*308 + nl] = v.z;
        sT[(dg*4+3)*308 + nl] = v.w;
    }
    __syncthreads();
    for (int wi = tid; wi < 64 * 80; wi += 256) {
        int kq = wi % 80, d = wi / 80;
        ushort4 o;
        int k = kq * 4;
        o.x = (k+0 < Nq) ? sT[d*308 + k+0] : (unsigned short)0;
        o.y = (k+1 < Nq) ? sT[d*308 + k+1] : (unsigned short)0;
        o.z = (k+2 < Nq) ? sT[d*308 + k+2] : (unsigned short)0;
        o.w = (k+3 < Nq) ? sT[d*308 + k+3] : (unsigned short)0;
        *(ushort4*)&Ht[((size_t)bt*64 + d)*NP + k] = o;
    }
}

// Fused A-recompute + aggregation. HOP=1: read te fp32, write teP bf16.
// HOP=2: read teP bf16. Operand-swapped agg MFMA -> ushort4 stores.
// Register-prefetch of next-c Hb fragments; hoisted ABt loads.
template<int HOP>
__global__ void __launch_bounds__(256) kfuse_t(
    const float* __restrict__ te,              // [B,N,T,D] fp32 (original input)
    unsigned short* __restrict__ teP,          // [bt][300][64] bf16 (HOP1 write / HOP2 read)
    const unsigned short* __restrict__ adjWb,  // [320][64]
    const float* __restrict__ adjBp,           // [320]
    const unsigned* __restrict__ ABt,          // tiled pairs
    const unsigned short* __restrict__ Hb_t,   // [bt][64][320]
    unsigned short* __restrict__ Hout_nb)      // [300][384][64]
{
    __shared__ unsigned short sPl[2][80 * 72];
    const int bt = blockIdx.x >> 2, qi = blockIdx.x & 3;
    const int b = bt / Tq, t = bt - b * Tq;
    const int nbase = qi * 80;
    const int tid = threadIdx.x;
    const int w = tid >> 6, lane = tid & 63, quad = lane >> 4, l16 = lane & 15;
    const int dcol = w*16 + l16;

    bf8_t tb0[5], tb1[5];
    #pragma unroll
    for (int nt = 0; nt < 5; ++nt) {
        int n = nbase + nt*16 + l16; if (n > Nq-1) n = Nq-1;
        if (HOP == 1) {
            const float* ter = te + (((size_t)b*Nq + n)*Tq + t)*Dq;
            tb0[nt] = pack8(ld4(ter + quad*8),      ld4(ter + quad*8 + 4));
            tb1[nt] = pack8(ld4(ter + 32 + quad*8), ld4(ter + 36 + quad*8));
            if (w == 0) {
                *(bf8_t*)&teP[((size_t)bt*Nq + n)*64 + quad*8] = tb0[nt];
                *(bf8_t*)&teP[((size_t)bt*Nq + n)*64 + 32 + quad*8] = tb1[nt];
            }
        } else {
            const unsigned short* tr = teP + ((size_t)bt*Nq + n)*64;
            tb0[nt] = *(const bf8_t*)(tr + quad*8);
            tb1[nt] = *(const bf8_t*)(tr + 32 + quad*8);
        }
    }
    f4_t accO[5];
    #pragma unroll
    for (int rt = 0; rt < 5; ++rt) accO[rt] = (f4_t){0.f, 0.f, 0.f, 0.f};

    const unsigned short* hr = Hb_t + ((size_t)bt*64 + dcol)*NP;
    bf8_t hv0 = *(const bf8_t*)(hr + quad*8);
    bf8_t hv1 = *(const bf8_t*)(hr + 32 + quad*8);

    for (int c = 0; c < 5; ++c) {
        const int cbase = c * 64;
        // prefetch next-c Hb fragments (consumed after next barrier)
        bf8_t nhv0, nhv1;
        if (c < 4) {
            nhv0 = *(const bf8_t*)(hr + cbase + 64 + quad*8);
            nhv1 = *(const bf8_t*)(hr + cbase + 96 + quad*8);
        }
        // hoisted ABt loads: all 5 in flight before the P-MFMA/sin chain
        const unsigned* abbase = ABt + ((((size_t)qi*5 + c)*4 + w)*5)*256 + lane*4;
        uint4 abv[5];
        #pragma unroll
        for (int nt = 0; nt < 5; ++nt) abv[nt] = *(const uint4*)(abbase + nt*256);
        const unsigned short* ar = adjWb + (cbase + w*16 + l16)*64;
        bf8_t ka0 = *(const bf8_t*)(ar + quad*8);
        bf8_t ka1 = *(const bf8_t*)(ar + 32 + quad*8);
        float4 bias4 = ld4(adjBp + cbase + w*16 + quad*4);
        unsigned short* sp = sPl[c & 1];
        #pragma unroll
        for (int nt = 0; nt < 5; ++nt) {
            f4_t p = {0.f, 0.f, 0.f, 0.f};
            p = __builtin_amdgcn_mfma_f32_16x16x32_bf16(ka0, tb0[nt], p, 0, 0, 0);
            p = __builtin_amdgcn_mfma_f32_16x16x32_bf16(ka1, tb1[nt], p, 0, 0, 0);
            uint4 ab = abv[nt];
            ushort4 o4;
            {
                float sv = __sinf(p[0] + bias4.x);
                o4.x = f2bf(fmaxf(fmaf(__uint_as_float(ab.x << 16), sv,
                                       __uint_as_float(ab.x & 0xFFFF0000u)), 0.f));
            }
            {
                float sv = __sinf(p[1] + bias4.y);
                o4.y = f2bf(fmaxf(fmaf(__uint_as_float(ab.y << 16), sv,
                                       __uint_as_float(ab.y & 0xFFFF0000u)), 0.f));
            }
            {
                float sv = __sinf(p[2] + bias4.z);
                o4.z = f2bf(fmaxf(fmaf(__uint_as_float(ab.z << 16), sv,
                                       __uint_as_float(ab.z & 0xFFFF0000u)), 0.f));
            }
            {
                float sv = __sinf(p[3] + bias4.w);
                o4.w = f2bf(fmaxf(fmaf(__uint_as_float(ab.w << 16), sv,
                                       __uint_as_float(ab.w & 0xFFFF0000u)), 0.f));
            }
            *(ushort4*)&sp[(nt*16 + l16)*72 + w*16 + quad*4] = o4;
        }
        __syncthreads();
        #pragma unroll
        for (int rt = 0; rt < 5; ++rt) {
            bf8_t p0 = *(const bf8_t*)&sp[(rt*16 + l16)*72 + quad*8];
            bf8_t p1 = *(const bf8_t*)&sp[(rt*16 + l16)*72 + 32 + quad*8];
            // swapped operands: D rows -> d (w*16+quad*4+reg), cols -> n (l16)
            accO[rt] = __builtin_amdgcn_mfma_f32_16x16x32_bf16(hv0, p0, accO[rt], 0, 0, 0);
            accO[rt] = __builtin_amdgcn_mfma_f32_16x16x32_bf16(hv1, p1, accO[rt], 0, 0, 0);
        }
        if (c < 4) { hv0 = nhv0; hv1 = nhv1; }
    }
    #pragma unroll
    for (int rt = 0; rt < 5; ++rt) {
        int n = nbase + rt*16 + l16;
        if (n < Nq) {
            ushort4 o;
            o.x = f2bf(accO[rt][0]); o.y = f2bf(accO[rt][1]);
            o.z = f2bf(accO[rt][2]); o.w = f2bf(accO[rt][3]);
            *(ushort4*)&Hout_nb[((size_t)n*BTq + bt)*64 + w*16 + quad*4] = o;
        }
    }
}

// Per-node matmul + gate. grid 1200 = (n, bt-quarter of 96).
// Operand-swapped MFMA -> ushort4 loads/stores in epilogue. In-place safe per block.
__global__ void __launch_bounds__(256) kmm(
    const unsigned short* __restrict__ Hagg_nb,  // [n][384][64]
    const unsigned short* __restrict__ Xp_nb,    // [n][384][64]
    const unsigned short* __restrict__ Wt,       // [n][64][64]
    unsigned short* __restrict__ Hout_nb)        // [n][384][64]
{
    const int n = blockIdx.x >> 2, qi = blockIdx.x & 3;
    const int bt0 = qi * 96;
    const int tid = threadIdx.x;
    const int w = tid >> 6, lane = tid & 63, quad = lane >> 4, l16 = lane & 15;
    const int dcol = w*16 + l16;
    const unsigned short* wn = Wt + (size_t)n * DDq + dcol*64;
    bf8_t v0 = *(const bf8_t*)(wn + quad*8);
    bf8_t v1 = *(const bf8_t*)(wn + 32 + quad*8);
    // hoist all 12 row-fragment loads before the MFMA chain
    bf8_t a0[6], a1[6];
    #pragma unroll
    for (int rt = 0; rt < 6; ++rt) {
        int r = bt0 + rt*16 + l16;
        const unsigned short* row = Hagg_nb + ((size_t)n*BTq + r)*64;
        a0[rt] = *(const bf8_t*)(row + quad*8);
        a1[rt] = *(const bf8_t*)(row + 32 + quad*8);
    }
    f4_t acc[6];
    #pragma unroll
    for (int rt = 0; rt < 6; ++rt) acc[rt] = (f4_t){0.f, 0.f, 0.f, 0.f};
    #pragma unroll
    for (int rt = 0; rt < 6; ++rt) {
        // swapped: D rows -> d (w*16+quad*4+reg), cols -> bt row (l16)
        acc[rt] = __builtin_amdgcn_mfma_f32_16x16x32_bf16(v0, a0[rt], acc[rt], 0, 0, 0);
        acc[rt] = __builtin_amdgcn_mfma_f32_16x16x32_bf16(v1, a1[rt], acc[rt], 0, 0, 0);
    }
    __syncthreads();   // all reads of Hagg done before in-place overwrite
    ushort4 xp4[6];
    #pragma unroll
    for (int rt = 0; rt < 6; ++rt) {
        int r = bt0 + rt*16 + l16;
        xp4[rt] = *(const ushort4*)&Xp_nb[((size_t)n*BTq + r)*64 + w*16 + quad*4];
    }
    #pragma unroll
    for (int rt = 0; rt < 6; ++rt) {
        int r = bt0 + rt*16 + l16;
        ushort4 o;
        o.x = f2bf(gatef(bf2f(xp4[rt].x) + acc[rt][0]));
        o.y = f2bf(gatef(bf2f(xp4[rt].y) + acc[rt][1]));
        o.z = f2bf(gatef(bf2f(xp4[rt].z) + acc[rt][2]));
        o.w = f2bf(gatef(bf2f(xp4[rt].w) + acc[rt][3]));
        *(ushort4*)&Hout_nb[((size_t)n*BTq + r)*64 + w*16 + quad*4] = o;
    }
}

// GCN epilogue: out[b,d,n,t] = gcnB[d] + [Xp|H1|H2]@gcnW[d,:].
// grid 1824 = (b, n-tile 19, row-group 3) for occupancy.
__global__ void __launch_bounds__(256) kgcn(
    const unsigned short* __restrict__ Xp_nb, const unsigned short* __restrict__ H1_nb,
    const unsigned short* __restrict__ H2_nb, const float* __restrict__ gcnW,
    const float* __restrict__ gcnB, float* __restrict__ out)
{
    const int bid = blockIdx.x;
    const int b = bid / 57, rem = bid % 57;
    const int tile = rem / 3, rg = rem % 3;
    const int n0 = tile * 16;
    const int rows = (tile == 18) ? 144 : 192;
    const int r0base = rg * 64;
    const int tid = threadIdx.x;
    const int w = tid >> 6, lane = tid & 63, quad = lane >> 4, l16 = lane & 15;
    const int dcol = w*16 + l16;
    const float bias = gcnB[dcol];
    f4_t acc[4];
    #pragma unroll
    for (int rt = 0; rt < 4; ++rt) acc[rt] = (f4_t){0.f, 0.f, 0.f, 0.f};
    const unsigned short* bufs[3] = {Xp_nb, H1_nb, H2_nb};
    #pragma unroll
    for (int c = 0; c < 3; ++c) {
        const unsigned short* buf = bufs[c];
        const float* gwr = gcnW + (size_t)dcol*Fq + c*Dq;
        bf8_t v0 = pack8(ld4(gwr + quad*8),      ld4(gwr + quad*8 + 4));
        bf8_t v1 = pack8(ld4(gwr + 32 + quad*8), ld4(gwr + 36 + quad*8));
        #pragma unroll
        for (int rt = 0; rt < 4; ++rt) {
            int rr = r0base + rt*16;
            if (rr < rows) {
                int r = rr + l16;
                int nl = r / 12, t = r - nl*12;
                int n = n0 + nl; if (n > Nq-1) n = Nq-1;
                const unsigned short* row = buf + ((size_t)n*BTq + b*Tq + t)*64;
                bf8_t a0 = *(const bf8_t*)(row + quad*8);
                bf8_t a1 = *(const bf8_t*)(row + 32 + quad*8);
                acc[rt] = __builtin_amdgcn_mfma_f32_16x16x32_bf16(a0, v0, acc[rt], 0, 0, 0);
                acc[rt] = __builtin_amdgcn_mfma_f32_16x16x32_bf16(a1, v1, acc[rt], 0, 0, 0);
            }
        }
    }
    float* outd = out + (size_t)(b*Dq + dcol)*3600 + n0*12;
    #pragma unroll
    for (int rt = 0; rt < 4; ++rt) {
        int rr = r0base + rt*16;
        if (rr < rows) {
            int r0 = rr + quad*4;
            float4 o = make_float4(acc[rt][0] + bias, acc[rt][1] + bias,
                                   acc[rt][2] + bias, acc[rt][3] + bias);
            *(float4*)&outd[r0] = o;
        }
    }
}

extern "C" void kernel_launch(void* const* d_in, const int* in_sizes, int n_in,
                              void* d_out, int out_size, void* d_ws, size_t ws_size,
                              hipStream_t stream) {
    (void)in_sizes; (void)n_in; (void)out_size; (void)ws_size;
    const float* X    = (const float*)d_in[0];
    const float* te   = (const float*)d_in[1];
    const float* adjW = (const float*)d_in[2];
    const float* adjB = (const float*)d_in[3];
    const float* w1   = (const float*)d_in[4];
    const float* w2   = (const float*)d_in[5];
    const float* a1   = (const float*)d_in[6];
    const float* a2   = (const float*)d_in[7];
    const float* b1   = (const float*)d_in[8];
    const float* b2   = (const float*)d_in[9];
    const float* gW   = (const float*)d_in[10];
    const float* gB   = (const float*)d_in[11];
    float* out = (float*)d_out;

    char* ws = (char*)d_ws;
    unsigned*       ABt    = (unsigned*)      (ws);               //    409,600
    unsigned short* adjWb  = (unsigned short*)(ws + 409600);      //  +  40,960 =    450,560
    float*          adjBp  = (float*)         (ws + 450560);      //  +   1,280 =    451,840
    unsigned short* Wt     = (unsigned short*)(ws + 451840);      //  +2,457,600 =  2,909,440
    unsigned short* Xp_t   = (unsigned short*)(ws + 2909440);     // +15,728,640 = 18,638,080
    unsigned short* Xp_nb  = (unsigned short*)(ws + 18638080);    // +14,745,600 = 33,383,680
    unsigned short* Hagg   = (unsigned short*)(ws + 33383680);    // +14,745,600 = 48,129,280
    unsigned short* H1_nb  = (unsigned short*)(ws + 48129280);    // +14,745,600 = 62,874,880
    unsigned short* H1_t   = (unsigned short*)(ws + 62874880);    // +15,728,640 = 78,603,520
    unsigned short* teP    = (unsigned short*)(ws + 78603520);    // +14,745,600 = 93,349,120 B

    hipLaunchKernelGGL(kprep_all, dim3(1548), dim3(256), 0, stream,
                       a1, a2, b1, b2, w1, w2, adjW, adjB, X,
                       ABt, Wt, adjWb, adjBp, Xp_t, Xp_nb);
    // hop 1 (writes teP bf16 for hop 2)
    hipLaunchKernelGGL(HIP_KERNEL_NAME(kfuse_t<1>), dim3(1536), dim3(256), 0, stream,
                       te, teP, adjWb, adjBp, ABt, Xp_t, Hagg);
    hipLaunchKernelGGL(kmm,   dim3(1200), dim3(256), 0, stream, Hagg, Xp_nb, Wt, H1_nb);
    hipLaunchKernelGGL(ktr2,  dim3(384),  dim3(256), 0, stream, H1_nb, H1_t);
    // hop 2 (reads teP bf16)
    hipLaunchKernelGGL(HIP_KERNEL_NAME(kfuse_t<2>), dim3(1536), dim3(256), 0, stream,
                       te, teP, adjWb, adjBp, ABt, H1_t, Hagg);
    hipLaunchKernelGGL(kmm,   dim3(1200), dim3(256), 0, stream, Hagg, Xp_nb, Wt, Hagg); // in-place -> H2
    // gcn epilogue
    hipLaunchKernelGGL(kgcn,  dim3(1824), dim3(256), 0, stream, Xp_nb, H1_nb, Hagg, gW, gB, out);
}